// Round 1
// baseline (558.085 us; speedup 1.0000x reference)
//
#include <hip/hip_runtime.h>
#include <math.h>

#define NH 512
#define BATCH 256
#define TT 512
#define NSTEPS (TT - 1)          // 511 recurrence steps
#define ALPHA 0.2f
#define OMA 0.8f
// sqrt(2/0.2 * 0.2^2) = sqrt(0.4)
#define ISCALE 0.6324555320336759f

// ---------------- helpers ----------------

__device__ __forceinline__ float wave_reduce_sum(float v) {
#pragma unroll
    for (int m = 32; m >= 1; m >>= 1) v += __shfl_xor(v, m, 64);
    return v;
}

__device__ __forceinline__ unsigned long long enc_key(float v, int i) {
    // v >= 0: float bits are order-preserving
    return (((unsigned long long)__float_as_uint(v)) << 32) | (unsigned int)i;
}

// ---------------- setup: rank-2 factorization of W_rec ----------------
// ws layout: key1 @0 (8B), key2 @8 (8B), rn @64 (512 f), dv @2112 (512 f), P @4160 (1024 f)

// Row norms^2 + argmax via atomicMax on encoded key.
__global__ void k_rownorm(const float* __restrict__ W, unsigned long long* key1,
                          float* __restrict__ rn) {
    const int i = blockIdx.x, tid = threadIdx.x;
    const float4* row = (const float4*)(W + (size_t)i * NH);
    float acc = 0.f;
#pragma unroll
    for (int r = 0; r < 2; ++r) {
        float4 v = row[tid + 64 * r];
        acc = fmaf(v.x, v.x, fmaf(v.y, v.y, fmaf(v.z, v.z, fmaf(v.w, v.w, acc))));
    }
    acc = wave_reduce_sum(acc);
    if (tid == 0) {
        rn[i] = acc;
        atomicMax(key1, enc_key(acc, i));
    }
}

// d_i = <row i, row i1>; residual argmax -> i2.
__global__ void k_rowdot(const float* __restrict__ W, const unsigned long long* key1,
                         unsigned long long* key2, const float* __restrict__ rn,
                         float* __restrict__ dv) {
    const int i = blockIdx.x, tid = threadIdx.x;
    const int i1 = (int)(*key1 & 0xffffffffULL);
    const float4* rowi = (const float4*)(W + (size_t)i * NH);
    const float4* row1 = (const float4*)(W + (size_t)i1 * NH);
    float acc = 0.f;
#pragma unroll
    for (int r = 0; r < 2; ++r) {
        float4 a = rowi[tid + 64 * r];
        float4 b = row1[tid + 64 * r];
        acc = fmaf(a.x, b.x, fmaf(a.y, b.y, fmaf(a.z, b.z, fmaf(a.w, b.w, acc))));
    }
    acc = wave_reduce_sum(acc);
    if (tid == 0) {
        dv[i] = acc;
        float resid = rn[i] - acc * acc / rn[i1];
        if (i != i1) atomicMax(key2, enc_key(fmaxf(resid, 0.f), i));
    }
}

// Least-squares coefficients P[n,0:2] so that W[n,:] ~= P[n,0]*W[i1,:] + P[n,1]*W[i2,:].
// Stored pre-scaled by ALPHA.
__global__ void k_computeP(const float* __restrict__ W, const unsigned long long* key1,
                           const unsigned long long* key2, const float* __restrict__ rn,
                           const float* __restrict__ dv, float* __restrict__ P) {
    const int n = blockIdx.x, tid = threadIdx.x;
    const int i1 = (int)(*key1 & 0xffffffffULL);
    const int i2 = (int)(*key2 & 0xffffffffULL);
    const float4* rown = (const float4*)(W + (size_t)n * NH);
    const float4* row1 = (const float4*)(W + (size_t)i1 * NH);
    const float4* row2 = (const float4*)(W + (size_t)i2 * NH);
    float t0 = 0.f, t1 = 0.f;
#pragma unroll
    for (int r = 0; r < 2; ++r) {
        float4 a = rown[tid + 64 * r];
        float4 b = row1[tid + 64 * r];
        float4 c = row2[tid + 64 * r];
        t0 = fmaf(a.x, b.x, fmaf(a.y, b.y, fmaf(a.z, b.z, fmaf(a.w, b.w, t0))));
        t1 = fmaf(a.x, c.x, fmaf(a.y, c.y, fmaf(a.z, c.z, fmaf(a.w, c.w, t1))));
    }
    t0 = wave_reduce_sum(t0);
    t1 = wave_reduce_sum(t1);
    if (tid == 0) {
        float g11 = rn[i1], g22 = rn[i2], g12 = dv[i2];
        float det = fmaf(g11, g22, -g12 * g12);
        float inv = 1.f / det;
        P[2 * n]     = ALPHA * ((g22 * t0 - g12 * t1) * inv);
        P[2 * n + 1] = ALPHA * ((g11 * t1 - g12 * t0) * inv);
    }
}

// ---------------- main recurrence ----------------
// One wave per batch element. Lane owns 8 contiguous hidden units.
__launch_bounds__(64, 1)
__global__ void k_main(const float* __restrict__ u, const float* __restrict__ inoise,
                       const float* __restrict__ rnoise, const float* __restrict__ W_in,
                       const float* __restrict__ W, const float* __restrict__ b_rec,
                       const unsigned long long* key1, const unsigned long long* key2,
                       const float* __restrict__ P, float* __restrict__ out) {
    __shared__ float4 lds_x[TT / 2];  // 512 timesteps * 2 inputs = 1024 f = 256 float4
    const int b = blockIdx.x, lane = threadIdx.x;
    const int i1 = (int)(key1[0] & 0xffffffffULL);
    const int i2 = (int)(key2[0] & 0xffffffffULL);

    // precompute x[t, 0:2] = u + ISCALE*input_noise into LDS
    const float4* u4 = (const float4*)(u + (size_t)b * TT * 2);
    const float4* n4 = (const float4*)(inoise + (size_t)b * TT * 2);
#pragma unroll
    for (int r = 0; r < 4; ++r) {
        float4 a = u4[lane + 64 * r];
        float4 c = n4[lane + 64 * r];
        float4 x;
        x.x = fmaf(ISCALE, c.x, a.x);
        x.y = fmaf(ISCALE, c.y, a.y);
        x.z = fmaf(ISCALE, c.z, a.z);
        x.w = fmaf(ISCALE, c.w, a.w);
        lds_x[lane + 64 * r] = x;
    }
    __syncthreads();

    const int n0 = lane * 8;
    float aa0[8], aa1[8], q0[8], q1[8], w0[8], w1[8], cb[8], s[8];
#pragma unroll
    for (int j = 0; j < 8; ++j) {
        const int n = n0 + j;
        aa0[j] = P[2 * n];
        aa1[j] = P[2 * n + 1];
        q0[j] = W[(size_t)i1 * NH + n];
        q1[j] = W[(size_t)i2 * NH + n];
        w0[j] = ALPHA * W_in[2 * n];
        w1[j] = ALPHA * W_in[2 * n + 1];
        cb[j] = ALPHA * b_rec[n];
        s[j] = 0.f;
    }

    const float* nzb = rnoise + (size_t)b * TT * NH + n0;
    float* ob = out + (size_t)b * TT * NH + n0;

    // states[:,0,:] = 0
    float4 z = {0.f, 0.f, 0.f, 0.f};
    *(float4*)(ob) = z;
    *(float4*)(ob + 4) = z;

    constexpr int PD = 8;  // prefetch depth (slots); 16 KB in flight per wave
    float4 bA[PD], bB[PD];
#pragma unroll
    for (int k = 0; k < PD; ++k) {
        bA[k] = *(const float4*)(nzb + (size_t)k * NH);
        bB[k] = *(const float4*)(nzb + (size_t)k * NH + 4);
    }

    const float2* lx = (const float2*)lds_x;

    for (int tb = 0; tb < NSTEPS; tb += PD) {
#pragma unroll
        for (int k = 0; k < PD; ++k) {
            const int t = tb + k;
            if (t >= NSTEPS) break;

            float2 x = lx[t];

            // pull noise out of the slot, then refill it (t+PD)
            float nz[8];
            nz[0] = bA[k].x; nz[1] = bA[k].y; nz[2] = bA[k].z; nz[3] = bA[k].w;
            nz[4] = bB[k].x; nz[5] = bB[k].y; nz[6] = bB[k].z; nz[7] = bB[k].w;
            int tp = t + PD; if (tp > NSTEPS - 1) tp = NSTEPS - 1;
            bA[k] = *(const float4*)(nzb + (size_t)tp * NH);
            bB[k] = *(const float4*)(nzb + (size_t)tp * NH + 4);

            // rank-2 projection: r_k = sum_n relu(s_n) * W[i_k, n]
            float p0 = 0.f, p1 = 0.f;
#pragma unroll
            for (int j = 0; j < 8; ++j) {
                float rs = fmaxf(s[j], 0.f);
                p0 = fmaf(rs, q0[j], p0);
                p1 = fmaf(rs, q1[j], p1);
            }
#pragma unroll
            for (int m = 32; m >= 1; m >>= 1) {
                p0 += __shfl_xor(p0, m, 64);
                p1 += __shfl_xor(p1, m, 64);
            }

            // state update
#pragma unroll
            for (int j = 0; j < 8; ++j) {
                float v = fmaf(ALPHA, nz[j], cb[j]);
                v = fmaf(w0[j], x.x, v);
                v = fmaf(w1[j], x.y, v);
                v = fmaf(aa0[j], p0, v);
                v = fmaf(aa1[j], p1, v);
                s[j] = fmaf(OMA, s[j], v);
            }

            float4 oA = {s[0], s[1], s[2], s[3]};
            float4 oB = {s[4], s[5], s[6], s[7]};
            *(float4*)(ob + (size_t)(t + 1) * NH) = oA;
            *(float4*)(ob + (size_t)(t + 1) * NH + 4) = oB;
        }
    }
}

// ---------------- launch ----------------

extern "C" void kernel_launch(void* const* d_in, const int* in_sizes, int n_in,
                              void* d_out, int out_size, void* d_ws, size_t ws_size,
                              hipStream_t stream) {
    const float* u      = (const float*)d_in[0];
    const float* inoise = (const float*)d_in[1];
    const float* rnoise = (const float*)d_in[2];
    const float* W_in   = (const float*)d_in[3];
    const float* W      = (const float*)d_in[4];
    const float* b_rec  = (const float*)d_in[5];
    float* out = (float*)d_out;

    char* ws = (char*)d_ws;
    unsigned long long* key1 = (unsigned long long*)(ws + 0);
    unsigned long long* key2 = (unsigned long long*)(ws + 8);
    float* rn = (float*)(ws + 64);
    float* dv = (float*)(ws + 2112);
    float* P  = (float*)(ws + 4160);

    hipMemsetAsync(d_ws, 0, 16, stream);
    hipLaunchKernelGGL(k_rownorm, dim3(NH), dim3(64), 0, stream, W, key1, rn);
    hipLaunchKernelGGL(k_rowdot, dim3(NH), dim3(64), 0, stream, W, key1, key2, rn, dv);
    hipLaunchKernelGGL(k_computeP, dim3(NH), dim3(64), 0, stream, W, key1, key2, rn, dv, P);
    hipLaunchKernelGGL(k_main, dim3(BATCH), dim3(64), 0, stream,
                       u, inoise, rnoise, W_in, W, b_rec, key1, key2, P, out);
}

// Round 2
// 469.081 us; speedup vs baseline: 1.1897x; 1.1897x over previous
//
#include <hip/hip_runtime.h>
#include <math.h>

#define NH 512
#define BATCH 256
#define TT 512
#define NSTEPS 511           // recurrence steps (t = 0..510 produce states 1..511)
#define ALPHA 0.2f
#define OMA 0.8f
// sqrt(2/0.2 * 0.2^2) = sqrt(0.4)
#define ISCALE 0.6324555320336759f
#define PD 12                // noise prefetch depth (slots); 24 KB reads in flight/wave

typedef float vf4 __attribute__((ext_vector_type(4)));

// ---------------- helpers ----------------

__device__ __forceinline__ float wave_reduce_sum(float v) {
#pragma unroll
    for (int m = 32; m >= 1; m >>= 1) v += __shfl_xor(v, m, 64);
    return v;
}

__device__ __forceinline__ unsigned long long enc_key(float v, int i) {
    // v >= 0: float bits are order-preserving
    return (((unsigned long long)__float_as_uint(v)) << 32) | (unsigned int)i;
}

__device__ __forceinline__ unsigned long long wave_max_key(unsigned long long k) {
#pragma unroll
    for (int m = 32; m >= 1; m >>= 1) {
        unsigned long long o = __shfl_xor(k, m, 64);
        k = (o > k) ? o : k;
    }
    return k;
}

// argmax index over rn[0..511], computed redundantly per wave (deterministic)
__device__ __forceinline__ int scan_argmax_rn(const float* __restrict__ rn, int tid) {
    const float4* rn4 = (const float4*)rn;
    unsigned long long key = 0;
#pragma unroll
    for (int r = 0; r < 2; ++r) {
        float4 v = rn4[tid + 64 * r];
        int base = 4 * (tid + 64 * r);
        unsigned long long k0 = enc_key(v.x, base);
        unsigned long long k1 = enc_key(v.y, base + 1);
        unsigned long long k2 = enc_key(v.z, base + 2);
        unsigned long long k3 = enc_key(v.w, base + 3);
        k0 = k0 > k1 ? k0 : k1;
        k2 = k2 > k3 ? k2 : k3;
        k0 = k0 > k2 ? k0 : k2;
        key = key > k0 ? key : k0;
    }
    return (int)(wave_max_key(key) & 0xffffffffULL);
}

// full-wave sum via DPP (VALU pipe, no LDS): result valid in lane 63
__device__ __forceinline__ float dpp_sum63(float v) {
    v += __int_as_float(__builtin_amdgcn_update_dpp(0, __float_as_int(v), 0x111, 0xf, 0xf, true)); // row_shr:1
    v += __int_as_float(__builtin_amdgcn_update_dpp(0, __float_as_int(v), 0x112, 0xf, 0xf, true)); // row_shr:2
    v += __int_as_float(__builtin_amdgcn_update_dpp(0, __float_as_int(v), 0x114, 0xf, 0xf, true)); // row_shr:4
    v += __int_as_float(__builtin_amdgcn_update_dpp(0, __float_as_int(v), 0x118, 0xf, 0xf, true)); // row_shr:8
    v += __int_as_float(__builtin_amdgcn_update_dpp(0, __float_as_int(v), 0x142, 0xa, 0xf, true)); // row_bcast15
    v += __int_as_float(__builtin_amdgcn_update_dpp(0, __float_as_int(v), 0x143, 0xc, 0xf, true)); // row_bcast31
    return v;
}

// ---------------- setup: rank-2 factorization of W_rec ----------------
// ws layout: idx @0 (2 ints), rn @64 (512 f), dv @2112 (512 f), P @4160 (1024 f)

__global__ void k_rownorm(const float* __restrict__ W, float* __restrict__ rn) {
    const int i = blockIdx.x, tid = threadIdx.x;
    const float4* row = (const float4*)(W + (size_t)i * NH);
    float acc = 0.f;
#pragma unroll
    for (int r = 0; r < 2; ++r) {
        float4 v = row[tid + 64 * r];
        acc = fmaf(v.x, v.x, fmaf(v.y, v.y, fmaf(v.z, v.z, fmaf(v.w, v.w, acc))));
    }
    acc = wave_reduce_sum(acc);
    if (tid == 0) rn[i] = acc;
}

__global__ void k_rowdot(const float* __restrict__ W, const float* __restrict__ rn,
                         float* __restrict__ dv) {
    const int i = blockIdx.x, tid = threadIdx.x;
    const int i1 = scan_argmax_rn(rn, tid);
    const float4* rowi = (const float4*)(W + (size_t)i * NH);
    const float4* row1 = (const float4*)(W + (size_t)i1 * NH);
    float acc = 0.f;
#pragma unroll
    for (int r = 0; r < 2; ++r) {
        float4 a = rowi[tid + 64 * r];
        float4 b = row1[tid + 64 * r];
        acc = fmaf(a.x, b.x, fmaf(a.y, b.y, fmaf(a.z, b.z, fmaf(a.w, b.w, acc))));
    }
    acc = wave_reduce_sum(acc);
    if (tid == 0) dv[i] = acc;
}

// Least-squares P[n,0:2] (pre-scaled by ALPHA): W[n,:] ~= c0*W[i1,:] + c1*W[i2,:]
__global__ void k_computeP(const float* __restrict__ W, const float* __restrict__ rn,
                           const float* __restrict__ dv, float* __restrict__ P,
                           int* __restrict__ idx) {
    const int n = blockIdx.x, tid = threadIdx.x;
    const int i1 = scan_argmax_rn(rn, tid);
    const float rn1 = rn[i1];
    const float inv1 = 1.f / rn1;

    // residual argmax -> i2 (exclude i1)
    const float4* rn4 = (const float4*)rn;
    const float4* dv4 = (const float4*)dv;
    unsigned long long key = 0;
#pragma unroll
    for (int r = 0; r < 2; ++r) {
        float4 a = rn4[tid + 64 * r];
        float4 d = dv4[tid + 64 * r];
        int base = 4 * (tid + 64 * r);
        float r0 = fmaxf(a.x - d.x * d.x * inv1, 0.f);
        float r1 = fmaxf(a.y - d.y * d.y * inv1, 0.f);
        float r2 = fmaxf(a.z - d.z * d.z * inv1, 0.f);
        float r3 = fmaxf(a.w - d.w * d.w * inv1, 0.f);
        unsigned long long k0 = (base + 0 != i1) ? enc_key(r0, base + 0) : 0ULL;
        unsigned long long k1 = (base + 1 != i1) ? enc_key(r1, base + 1) : 0ULL;
        unsigned long long k2 = (base + 2 != i1) ? enc_key(r2, base + 2) : 0ULL;
        unsigned long long k3 = (base + 3 != i1) ? enc_key(r3, base + 3) : 0ULL;
        k0 = k0 > k1 ? k0 : k1;
        k2 = k2 > k3 ? k2 : k3;
        k0 = k0 > k2 ? k0 : k2;
        key = key > k0 ? key : k0;
    }
    const int i2 = (int)(wave_max_key(key) & 0xffffffffULL);

    const float4* rown = (const float4*)(W + (size_t)n * NH);
    const float4* row1 = (const float4*)(W + (size_t)i1 * NH);
    const float4* row2 = (const float4*)(W + (size_t)i2 * NH);
    float t0 = 0.f, t1 = 0.f;
#pragma unroll
    for (int r = 0; r < 2; ++r) {
        float4 a = rown[tid + 64 * r];
        float4 b = row1[tid + 64 * r];
        float4 c = row2[tid + 64 * r];
        t0 = fmaf(a.x, b.x, fmaf(a.y, b.y, fmaf(a.z, b.z, fmaf(a.w, b.w, t0))));
        t1 = fmaf(a.x, c.x, fmaf(a.y, c.y, fmaf(a.z, c.z, fmaf(a.w, c.w, t1))));
    }
    t0 = wave_reduce_sum(t0);
    t1 = wave_reduce_sum(t1);
    if (tid == 0) {
        float g11 = rn1, g22 = rn[i2], g12 = dv[i2];
        float det = fmaf(g11, g22, -g12 * g12);
        float inv = 1.f / det;
        P[2 * n]     = ALPHA * ((g22 * t0 - g12 * t1) * inv);
        P[2 * n + 1] = ALPHA * ((g11 * t1 - g12 * t0) * inv);
        if (n == 0) { idx[0] = i1; idx[1] = i2; }
    }
}

// ---------------- main recurrence ----------------
// One wave per batch element; lane owns 8 contiguous hidden units.
// Loop-carried critical path: fmax -> mul -> 3 tree adds -> 6 DPP adds
// -> readlane -> 2 FMA  (~14 VALU ops; decay+input terms folded into base[]
// off the critical path).
__launch_bounds__(64, 1)
__global__ void k_main(const float* __restrict__ u, const float* __restrict__ inoise,
                       const float* __restrict__ rnoise, const float* __restrict__ W_in,
                       const float* __restrict__ W, const float* __restrict__ b_rec,
                       const int* __restrict__ idx, const float* __restrict__ P,
                       float* __restrict__ out) {
    __shared__ float2 lds_x[TT];  // x[t,0:2] = u + ISCALE*input_noise
    const int b = blockIdx.x, lane = threadIdx.x;
    const int i1 = idx[0];
    const int i2 = idx[1];

    const float4* u4 = (const float4*)(u + (size_t)b * TT * 2);
    const float4* n4 = (const float4*)(inoise + (size_t)b * TT * 2);
    float4* lx4 = (float4*)lds_x;
#pragma unroll
    for (int r = 0; r < 4; ++r) {
        float4 a = u4[lane + 64 * r];
        float4 c = n4[lane + 64 * r];
        float4 x;
        x.x = fmaf(ISCALE, c.x, a.x);
        x.y = fmaf(ISCALE, c.y, a.y);
        x.z = fmaf(ISCALE, c.z, a.z);
        x.w = fmaf(ISCALE, c.w, a.w);
        lx4[lane + 64 * r] = x;
    }
    __syncthreads();

    const int n0 = lane * 8;
    float aa0[8], aa1[8], q0[8], q1[8], w0[8], w1[8], cb[8], s[8];
#pragma unroll
    for (int j = 0; j < 8; ++j) {
        const int n = n0 + j;
        aa0[j] = P[2 * n];
        aa1[j] = P[2 * n + 1];
        q0[j] = W[(size_t)i1 * NH + n];
        q1[j] = W[(size_t)i2 * NH + n];
        w0[j] = ALPHA * W_in[2 * n];
        w1[j] = ALPHA * W_in[2 * n + 1];
        cb[j] = ALPHA * b_rec[n];
        s[j] = 0.f;
    }

    const float* nzb = rnoise + (size_t)b * TT * NH + n0;
    float* ob = out + (size_t)b * TT * NH + n0;

    // states[:,0,:] = 0
    vf4 z = {0.f, 0.f, 0.f, 0.f};
    __builtin_nontemporal_store(z, (vf4*)ob);
    __builtin_nontemporal_store(z, (vf4*)(ob + 4));

    float4 bA[PD], bB[PD];
#pragma unroll
    for (int k = 0; k < PD; ++k) {
        bA[k] = *(const float4*)(nzb + (size_t)k * NH);
        bB[k] = *(const float4*)(nzb + (size_t)k * NH + 4);
    }

#define STEP(t_, k_, REFILL_)                                                        \
    {                                                                                \
        const int t = (t_);                                                          \
        float2 x = lds_x[t];                                                         \
        float nz[8];                                                                 \
        nz[0] = bA[k_].x; nz[1] = bA[k_].y; nz[2] = bA[k_].z; nz[3] = bA[k_].w;      \
        nz[4] = bB[k_].x; nz[5] = bB[k_].y; nz[6] = bB[k_].z; nz[7] = bB[k_].w;      \
        if (REFILL_) {                                                               \
            int tp = t + PD; if (tp > NSTEPS) tp = NSTEPS; /* row 511 is valid */    \
            bA[k_] = *(const float4*)(nzb + (size_t)tp * NH);                        \
            bB[k_] = *(const float4*)(nzb + (size_t)tp * NH + 4);                    \
        }                                                                            \
        float base_[8], m0[8], m1[8];                                                \
        _Pragma("unroll")                                                            \
        for (int j = 0; j < 8; ++j) {                                                \
            float rs = fmaxf(s[j], 0.f);                                             \
            m0[j] = rs * q0[j];                                                      \
            m1[j] = rs * q1[j];                                                      \
            float v = fmaf(ALPHA, nz[j], cb[j]);                                     \
            v = fmaf(w0[j], x.x, v);                                                 \
            v = fmaf(w1[j], x.y, v);                                                 \
            base_[j] = fmaf(OMA, s[j], v);                                           \
        }                                                                            \
        float a0 = ((m0[0] + m0[1]) + (m0[2] + m0[3])) +                             \
                   ((m0[4] + m0[5]) + (m0[6] + m0[7]));                              \
        float a1 = ((m1[0] + m1[1]) + (m1[2] + m1[3])) +                             \
                   ((m1[4] + m1[5]) + (m1[6] + m1[7]));                              \
        float r0 = dpp_sum63(a0);                                                    \
        float r1 = dpp_sum63(a1);                                                    \
        float p0 = __int_as_float(__builtin_amdgcn_readlane(__float_as_int(r0), 63));\
        float p1 = __int_as_float(__builtin_amdgcn_readlane(__float_as_int(r1), 63));\
        _Pragma("unroll")                                                            \
        for (int j = 0; j < 8; ++j) {                                                \
            float v = fmaf(aa0[j], p0, base_[j]);                                    \
            s[j] = fmaf(aa1[j], p1, v);                                              \
        }                                                                            \
        vf4 oA = {s[0], s[1], s[2], s[3]};                                           \
        vf4 oB = {s[4], s[5], s[6], s[7]};                                           \
        __builtin_nontemporal_store(oA, (vf4*)(ob + (size_t)(t + 1) * NH));          \
        __builtin_nontemporal_store(oB, (vf4*)(ob + (size_t)(t + 1) * NH + 4));      \
    }

    // 511 = 42*12 + 7: full blocks cover t in [0,504), tail covers [504,511)
    for (int tb = 0; tb < 504; tb += PD) {
#pragma unroll
        for (int k = 0; k < PD; ++k) STEP(tb + k, k, true)
    }
#pragma unroll
    for (int k = 0; k < 7; ++k) STEP(504 + k, k, false)

#undef STEP
}

// ---------------- launch ----------------

extern "C" void kernel_launch(void* const* d_in, const int* in_sizes, int n_in,
                              void* d_out, int out_size, void* d_ws, size_t ws_size,
                              hipStream_t stream) {
    const float* u      = (const float*)d_in[0];
    const float* inoise = (const float*)d_in[1];
    const float* rnoise = (const float*)d_in[2];
    const float* W_in   = (const float*)d_in[3];
    const float* W      = (const float*)d_in[4];
    const float* b_rec  = (const float*)d_in[5];
    float* out = (float*)d_out;

    char* ws = (char*)d_ws;
    int* idx  = (int*)(ws + 0);
    float* rn = (float*)(ws + 64);
    float* dv = (float*)(ws + 2112);
    float* P  = (float*)(ws + 4160);

    hipLaunchKernelGGL(k_rownorm, dim3(NH), dim3(64), 0, stream, W, rn);
    hipLaunchKernelGGL(k_rowdot, dim3(NH), dim3(64), 0, stream, W, rn, dv);
    hipLaunchKernelGGL(k_computeP, dim3(NH), dim3(64), 0, stream, W, rn, dv, P, idx);
    hipLaunchKernelGGL(k_main, dim3(BATCH), dim3(64), 0, stream,
                       u, inoise, rnoise, W_in, W, b_rec, idx, P, out);
}